// Round 1
// baseline (3471.623 us; speedup 1.0000x reference)
//
#include <hip/hip_runtime.h>
#include <math.h>

#define BB 32
#define FF 256
#define N1 64
#define N2 256

// ws layout (float offsets)
#define OFF_INVT 0            // 32*64      = 2048
#define OFF_INVS 2048         // 32*256     = 8192  -> 10240
#define OFF_W1T  10240        // 260*256    = 66560 -> 76800
#define OFF_W2T  76800        // 256*256    = 65536 -> 142336
#define OFF_W3T  142336       // -> 207872
#define OFF_W4T  207872       // -> 273408
#define OFF_W5T  273408       // -> 338944
#define OFF_SIM  338944       // 32*64*256  = 524288 -> 863232
#define OFF_C1   863232       // 32*64*256  = 524288 -> 1387520
#define OFF_POOL 1387520      // 32*256*256 = 2097152 -> 3484672 (~13.9 MB)

// Transpose weights into k-major layouts for coalesced staging.
__global__ void k_prep(const float* __restrict__ W1, const float* __restrict__ W2,
                       const float* __restrict__ W3, const float* __restrict__ W4,
                       const float* __restrict__ W5, float* __restrict__ ws) {
  int c = blockIdx.x;   // input-channel index
  int w = blockIdx.y;   // which weight
  int o = threadIdx.x;  // output channel
  if (w == 0) {
    ws[OFF_W1T + c * 256 + o] = W1[o * 260 + c];
  } else if (c < 256) {
    const float* W = (w == 1) ? W2 : (w == 2) ? W3 : (w == 3) ? W4 : W5;
    int off = (w == 1) ? OFF_W2T : (w == 2) ? OFF_W3T : (w == 3) ? OFF_W4T : OFF_W5T;
    ws[off + c * 256 + o] = W[o * 256 + c];
  }
}

// Inverse norms (clamped at 1e-8) for template and search features.
__global__ void k_norms(const float* __restrict__ s, const float* __restrict__ t,
                        float* __restrict__ ws) {
  int b = blockIdx.x, tid = threadIdx.x;
  {
    const float* sp = s + b * FF * N2 + tid;
    float acc = 0.f;
#pragma unroll 4
    for (int f = 0; f < FF; ++f) { float v = sp[f * N2]; acc = fmaf(v, v, acc); }
    ws[OFF_INVS + b * N2 + tid] = 1.0f / fmaxf(sqrtf(acc), 1e-8f);
  }
  if (tid < N1) {
    const float* tp = t + b * FF * N1 + tid;
    float acc = 0.f;
#pragma unroll 4
    for (int f = 0; f < FF; ++f) { float v = tp[f * N1]; acc = fmaf(v, v, acc); }
    ws[OFF_INVT + b * N1 + tid] = 1.0f / fmaxf(sqrtf(acc), 1e-8f);
  }
}

// sim[b,n,m] = <t_norm[b,:,n], s_norm[b,:,m]>
__global__ void k_sim(const float* __restrict__ t, const float* __restrict__ s,
                      float* __restrict__ ws) {
  int n = blockIdx.x, b = blockIdx.y, m = threadIdx.x;
  __shared__ float tl[FF];
  tl[m] = t[(b * FF + m) * N1 + n];   // thread m loads feature f=m of template point n
  __syncthreads();
  const float* sp = s + b * FF * N2 + m;
  float acc = 0.f;
#pragma unroll 4
  for (int f = 0; f < FF; ++f) acc = fmaf(tl[f], sp[f * N2], acc);
  ws[OFF_SIM + (b * N1 + n) * N2 + m] =
      acc * ws[OFF_INVT + b * N1 + n] * ws[OFF_INVS + b * N2 + m];
}

// c1[b,n,o] = b1[o] + W1[o,1:4]·seeds[b,n,:] + W1[o,4:260]·tfeat[b,:,n]
__global__ void k_c1(const float* __restrict__ t, const float* __restrict__ seeds,
                     const float* __restrict__ b1, float* __restrict__ ws) {
  int n = blockIdx.x, b = blockIdx.y, o = threadIdx.x;
  __shared__ float tl[FF];
  tl[o] = t[(b * FF + o) * N1 + n];
  __syncthreads();
  const float* w1T = ws + OFF_W1T;
  float s0 = seeds[(b * N1 + n) * 3 + 0];
  float s1 = seeds[(b * N1 + n) * 3 + 1];
  float s2 = seeds[(b * N1 + n) * 3 + 2];
  float acc = b1[o];
  acc = fmaf(w1T[1 * 256 + o], s0, acc);
  acc = fmaf(w1T[2 * 256 + o], s1, acc);
  acc = fmaf(w1T[3 * 256 + o], s2, acc);
#pragma unroll 4
  for (int k = 0; k < FF; ++k) acc = fmaf(w1T[(4 + k) * 256 + o], tl[k], acc);
  ws[OFF_C1 + (b * N1 + n) * 256 + o] = acc;
}

// Fused layers 1-3 + maxpool over n1.
// Grid (8, 32): 8 n2-tiles of 32 columns x 32 batches. 256 threads.
// Thread micro-tile: 8 output channels x 4 columns.
__global__ __launch_bounds__(256) void k_fused(const float* __restrict__ b2,
                                               const float* __restrict__ b3,
                                               float* __restrict__ ws) {
  const int mt = blockIdx.x, b = blockIdx.y;
  const int tid = threadIdx.x;
  const int og = tid >> 3, mg = tid & 7;
  const int o0 = og * 8, m0 = mg * 4;
  const int mb = mt * 32;

  __shared__ float ybuf[256 * 32];
  __shared__ float wbuf[32 * 256];
  __shared__ float c1row[256];
  __shared__ float w1c0[256];
  __shared__ float simrow[32];

  const float* w2T = ws + OFF_W2T;
  const float* w3T = ws + OFF_W3T;
  const float* simP = ws + OFF_SIM + (b * N1) * N2 + mb;
  const float* c1P = ws + OFF_C1 + (b * N1) * 256;
  float* poolP = ws + OFF_POOL + b * 256 * N2 + mb;

  w1c0[tid] = ws[OFF_W1T + tid];  // W1 column 0 (sim weight)

  float pool[8][4];
#pragma unroll
  for (int i = 0; i < 8; ++i)
#pragma unroll
    for (int j = 0; j < 4; ++j) pool[i][j] = 0.f;

  float bias2[8], bias3[8];
#pragma unroll
  for (int i = 0; i < 8; ++i) { bias2[i] = b2[o0 + i]; bias3[i] = b3[o0 + i]; }

  for (int n = 0; n < N1; ++n) {
    __syncthreads();  // guard c1row/simrow/ybuf overwrite vs previous iter reads
    c1row[tid] = c1P[n * 256 + tid];
    if (tid < 32) simrow[tid] = simP[n * N2 + tid];
    __syncthreads();

    // layer 1: ybuf[k][m] = relu(w1c0[k]*sim + c1[k])
    {
      const int m = tid & 31;
      const int kb = (tid >> 5) * 32;
      const float sv = simrow[m];
#pragma unroll
      for (int ki = 0; ki < 32; ++ki) {
        const int k = kb + ki;
        float v = fmaf(w1c0[k], sv, c1row[k]);
        ybuf[k * 32 + m] = v > 0.f ? v : 0.f;
      }
    }

    float acc[8][4];
#pragma unroll
    for (int i = 0; i < 8; ++i)
#pragma unroll
      for (int j = 0; j < 4; ++j) acc[i][j] = 0.f;

    // layer 2 GEMM
    for (int kt = 0; kt < 8; ++kt) {
      __syncthreads();
#pragma unroll 8
      for (int i = 0; i < 32; ++i) wbuf[i * 256 + tid] = w2T[(kt * 32 + i) * 256 + tid];
      __syncthreads();
#pragma unroll 8
      for (int kk = 0; kk < 32; ++kk) {
        const float4 y = *(const float4*)&ybuf[(kt * 32 + kk) * 32 + m0];
        const float4 wa = *(const float4*)&wbuf[kk * 256 + o0];
        const float4 wb = *(const float4*)&wbuf[kk * 256 + o0 + 4];
        const float wv[8] = {wa.x, wa.y, wa.z, wa.w, wb.x, wb.y, wb.z, wb.w};
#pragma unroll
        for (int i = 0; i < 8; ++i) {
          acc[i][0] = fmaf(wv[i], y.x, acc[i][0]);
          acc[i][1] = fmaf(wv[i], y.y, acc[i][1]);
          acc[i][2] = fmaf(wv[i], y.z, acc[i][2]);
          acc[i][3] = fmaf(wv[i], y.w, acc[i][3]);
        }
      }
    }
    __syncthreads();  // all ybuf reads done; safe to overwrite with y2
#pragma unroll
    for (int i = 0; i < 8; ++i)
#pragma unroll
      for (int j = 0; j < 4; ++j) {
        float v = acc[i][j] + bias2[i];
        ybuf[(o0 + i) * 32 + m0 + j] = v > 0.f ? v : 0.f;
      }

#pragma unroll
    for (int i = 0; i < 8; ++i)
#pragma unroll
      for (int j = 0; j < 4; ++j) acc[i][j] = 0.f;

    // layer 3 GEMM (first sync also publishes the y2 writes above)
    for (int kt = 0; kt < 8; ++kt) {
      __syncthreads();
#pragma unroll 8
      for (int i = 0; i < 32; ++i) wbuf[i * 256 + tid] = w3T[(kt * 32 + i) * 256 + tid];
      __syncthreads();
#pragma unroll 8
      for (int kk = 0; kk < 32; ++kk) {
        const float4 y = *(const float4*)&ybuf[(kt * 32 + kk) * 32 + m0];
        const float4 wa = *(const float4*)&wbuf[kk * 256 + o0];
        const float4 wb = *(const float4*)&wbuf[kk * 256 + o0 + 4];
        const float wv[8] = {wa.x, wa.y, wa.z, wa.w, wb.x, wb.y, wb.z, wb.w};
#pragma unroll
        for (int i = 0; i < 8; ++i) {
          acc[i][0] = fmaf(wv[i], y.x, acc[i][0]);
          acc[i][1] = fmaf(wv[i], y.y, acc[i][1]);
          acc[i][2] = fmaf(wv[i], y.z, acc[i][2]);
          acc[i][3] = fmaf(wv[i], y.w, acc[i][3]);
        }
      }
    }
#pragma unroll
    for (int i = 0; i < 8; ++i)
#pragma unroll
      for (int j = 0; j < 4; ++j) {
        float v = acc[i][j] + bias3[i];
        v = v > 0.f ? v : 0.f;
        pool[i][j] = fmaxf(pool[i][j], v);
      }
  }

#pragma unroll
  for (int i = 0; i < 8; ++i) {
    float4 v = {pool[i][0], pool[i][1], pool[i][2], pool[i][3]};
    *(float4*)&poolP[(o0 + i) * N2 + m0] = v;
  }
}

// Layers 4-5 on pooled (b,256,n2).
__global__ __launch_bounds__(256) void k_final(const float* __restrict__ b4,
                                               const float* __restrict__ b5,
                                               const float* __restrict__ ws,
                                               float* __restrict__ out) {
  const int mt = blockIdx.x, b = blockIdx.y;
  const int tid = threadIdx.x;
  const int og = tid >> 3, mg = tid & 7;
  const int o0 = og * 8, m0 = mg * 4;
  const int mb = mt * 32;

  __shared__ float ybuf[256 * 32];
  __shared__ float wbuf[32 * 256];

  const float* w4T = ws + OFF_W4T;
  const float* w5T = ws + OFF_W5T;
  const float* pooled = ws + OFF_POOL + b * 256 * N2 + mb;

  // stage pooled tile: ybuf[k][m]
#pragma unroll 8
  for (int i = 0; i < 32; ++i) {
    int e = i * 256 + tid;
    int k = e >> 5, m = e & 31;
    ybuf[k * 32 + m] = pooled[k * N2 + m];
  }

  float bias4[8], bias5[8];
#pragma unroll
  for (int i = 0; i < 8; ++i) { bias4[i] = b4[o0 + i]; bias5[i] = b5[o0 + i]; }

  float acc[8][4];
#pragma unroll
  for (int i = 0; i < 8; ++i)
#pragma unroll
    for (int j = 0; j < 4; ++j) acc[i][j] = 0.f;

  // layer 4 (leading sync of first kt publishes ybuf staging)
  for (int kt = 0; kt < 8; ++kt) {
    __syncthreads();
#pragma unroll 8
    for (int i = 0; i < 32; ++i) wbuf[i * 256 + tid] = w4T[(kt * 32 + i) * 256 + tid];
    __syncthreads();
#pragma unroll 8
    for (int kk = 0; kk < 32; ++kk) {
      const float4 y = *(const float4*)&ybuf[(kt * 32 + kk) * 32 + m0];
      const float4 wa = *(const float4*)&wbuf[kk * 256 + o0];
      const float4 wb = *(const float4*)&wbuf[kk * 256 + o0 + 4];
      const float wv[8] = {wa.x, wa.y, wa.z, wa.w, wb.x, wb.y, wb.z, wb.w};
#pragma unroll
      for (int i = 0; i < 8; ++i) {
        acc[i][0] = fmaf(wv[i], y.x, acc[i][0]);
        acc[i][1] = fmaf(wv[i], y.y, acc[i][1]);
        acc[i][2] = fmaf(wv[i], y.z, acc[i][2]);
        acc[i][3] = fmaf(wv[i], y.w, acc[i][3]);
      }
    }
  }
  __syncthreads();
#pragma unroll
  for (int i = 0; i < 8; ++i)
#pragma unroll
    for (int j = 0; j < 4; ++j) {
      float v = acc[i][j] + bias4[i];
      ybuf[(o0 + i) * 32 + m0 + j] = v > 0.f ? v : 0.f;
    }

#pragma unroll
  for (int i = 0; i < 8; ++i)
#pragma unroll
    for (int j = 0; j < 4; ++j) acc[i][j] = 0.f;

  // layer 5 (no relu)
  for (int kt = 0; kt < 8; ++kt) {
    __syncthreads();
#pragma unroll 8
    for (int i = 0; i < 32; ++i) wbuf[i * 256 + tid] = w5T[(kt * 32 + i) * 256 + tid];
    __syncthreads();
#pragma unroll 8
    for (int kk = 0; kk < 32; ++kk) {
      const float4 y = *(const float4*)&ybuf[(kt * 32 + kk) * 32 + m0];
      const float4 wa = *(const float4*)&wbuf[kk * 256 + o0];
      const float4 wb = *(const float4*)&wbuf[kk * 256 + o0 + 4];
      const float wv[8] = {wa.x, wa.y, wa.z, wa.w, wb.x, wb.y, wb.z, wb.w};
#pragma unroll
      for (int i = 0; i < 8; ++i) {
        acc[i][0] = fmaf(wv[i], y.x, acc[i][0]);
        acc[i][1] = fmaf(wv[i], y.y, acc[i][1]);
        acc[i][2] = fmaf(wv[i], y.z, acc[i][2]);
        acc[i][3] = fmaf(wv[i], y.w, acc[i][3]);
      }
    }
  }

#pragma unroll
  for (int i = 0; i < 8; ++i) {
    float4 v = {acc[i][0] + bias5[i], acc[i][1] + bias5[i], acc[i][2] + bias5[i],
                acc[i][3] + bias5[i]};
    *(float4*)&out[(b * 256 + o0 + i) * N2 + mb + m0] = v;
  }
}

extern "C" void kernel_launch(void* const* d_in, const int* in_sizes, int n_in,
                              void* d_out, int out_size, void* d_ws, size_t ws_size,
                              hipStream_t stream) {
  const float* sf = (const float*)d_in[0];
  const float* tf = (const float*)d_in[1];
  const float* seeds = (const float*)d_in[2];
  const float* W1 = (const float*)d_in[3];
  const float* b1 = (const float*)d_in[4];
  const float* W2 = (const float*)d_in[5];
  const float* b2 = (const float*)d_in[6];
  const float* W3 = (const float*)d_in[7];
  const float* b3 = (const float*)d_in[8];
  const float* W4 = (const float*)d_in[9];
  const float* b4 = (const float*)d_in[10];
  const float* W5 = (const float*)d_in[11];
  const float* b5 = (const float*)d_in[12];
  float* ws = (float*)d_ws;
  float* out = (float*)d_out;

  k_prep<<<dim3(260, 5), 256, 0, stream>>>(W1, W2, W3, W4, W5, ws);
  k_norms<<<dim3(BB), 256, 0, stream>>>(sf, tf, ws);
  k_sim<<<dim3(N1, BB), 256, 0, stream>>>(tf, sf, ws);
  k_c1<<<dim3(N1, BB), 256, 0, stream>>>(tf, seeds, b1, ws);
  k_fused<<<dim3(8, BB), 256, 0, stream>>>(b2, b3, ws);
  k_final<<<dim3(8, BB), 256, 0, stream>>>(b4, b5, ws, out);
}

// Round 2
// 245.582 us; speedup vs baseline: 14.1363x; 14.1363x over previous
//
#include <hip/hip_runtime.h>
#include <math.h>

#define BB 32
#define FF 256
#define N1 64
#define N2 256

typedef _Float16 f16;
typedef _Float16 f16x4 __attribute__((ext_vector_type(4)));
typedef _Float16 f16x8 __attribute__((ext_vector_type(8)));
typedef float f32x4 __attribute__((ext_vector_type(4)));

// ---- ws byte offsets ----
#define OFFB_W1T  0u          // 260*256*4 = 266240
#define OFFB_INVT 266240u     // 32*64*4   = 8192
#define OFFB_INVS 274432u     // 32*256*4  = 32768
#define OFFB_SIM  307200u     // 32*64*256*4 = 2097152
#define OFFB_C1   2404352u    // 32*64*256*4 = 2097152
#define OFFB_W2H  4501504u    // 256*256*2 = 131072
#define OFFB_W3H  4632576u
#define OFFB_W4H  4763648u
#define OFFB_W5H  4894720u    // end 5025792 (~5 MB)

// W1 transpose to [c][o] f32 (for k_c1 + w1c0 staging).
__global__ void k_prep_w1t(const float* __restrict__ W1, float* __restrict__ w1t) {
  int c = blockIdx.x, o = threadIdx.x;
  w1t[c * 256 + o] = W1[o * 260 + c];
}

// f16 copies of W2..W5 (row-major [o][k] — already fragment-friendly).
__global__ void k_half(const float* __restrict__ W2, const float* __restrict__ W3,
                       const float* __restrict__ W4, const float* __restrict__ W5,
                       f16* __restrict__ w2h, f16* __restrict__ w3h,
                       f16* __restrict__ w4h, f16* __restrict__ w5h) {
  int o = blockIdx.x, m = blockIdx.y, k = threadIdx.x;
  int idx = o * 256 + k;
  if (m == 0)      w2h[idx] = (f16)W2[idx];
  else if (m == 1) w3h[idx] = (f16)W3[idx];
  else if (m == 2) w4h[idx] = (f16)W4[idx];
  else             w5h[idx] = (f16)W5[idx];
}

// Inverse norms (clamped at 1e-8).
__global__ void k_norms(const float* __restrict__ s, const float* __restrict__ t,
                        float* __restrict__ invt, float* __restrict__ invs) {
  int b = blockIdx.x, tid = threadIdx.x;
  {
    const float* sp = s + b * FF * N2 + tid;
    float acc = 0.f;
#pragma unroll 4
    for (int f = 0; f < FF; ++f) { float v = sp[f * N2]; acc = fmaf(v, v, acc); }
    invs[b * N2 + tid] = 1.0f / fmaxf(sqrtf(acc), 1e-8f);
  }
  if (tid < N1) {
    const float* tp = t + b * FF * N1 + tid;
    float acc = 0.f;
#pragma unroll 4
    for (int f = 0; f < FF; ++f) { float v = tp[f * N1]; acc = fmaf(v, v, acc); }
    invt[b * N1 + tid] = 1.0f / fmaxf(sqrtf(acc), 1e-8f);
  }
}

// sim[b,n,m] (f32, exact cosine path kept in fp32 for accuracy)
__global__ void k_sim(const float* __restrict__ t, const float* __restrict__ s,
                      const float* __restrict__ invt, const float* __restrict__ invs,
                      float* __restrict__ sim) {
  int n = blockIdx.x, b = blockIdx.y, m = threadIdx.x;
  __shared__ float tl[FF];
  tl[m] = t[(b * FF + m) * N1 + n];
  __syncthreads();
  const float* sp = s + b * FF * N2 + m;
  float acc = 0.f;
#pragma unroll 4
  for (int f = 0; f < FF; ++f) acc = fmaf(tl[f], sp[f * N2], acc);
  sim[(b * N1 + n) * N2 + m] = acc * invt[b * N1 + n] * invs[b * N2 + m];
}

// c1[b,n,o] = b1[o] + W1[o,1:4]*seeds + W1[o,4:260]*tfeat[:,n]  (f32)
__global__ void k_c1(const float* __restrict__ t, const float* __restrict__ seeds,
                     const float* __restrict__ b1, const float* __restrict__ w1t,
                     float* __restrict__ c1) {
  int n = blockIdx.x, b = blockIdx.y, o = threadIdx.x;
  __shared__ float tl[FF];
  tl[o] = t[(b * FF + o) * N1 + n];
  __syncthreads();
  float s0 = seeds[(b * N1 + n) * 3 + 0];
  float s1 = seeds[(b * N1 + n) * 3 + 1];
  float s2 = seeds[(b * N1 + n) * 3 + 2];
  float acc = b1[o];
  acc = fmaf(w1t[1 * 256 + o], s0, acc);
  acc = fmaf(w1t[2 * 256 + o], s1, acc);
  acc = fmaf(w1t[3 * 256 + o], s2, acc);
#pragma unroll 4
  for (int k = 0; k < FF; ++k) acc = fmaf(w1t[(4 + k) * 256 + o], tl[k], acc);
  c1[(b * N1 + n) * 256 + o] = acc;
}

#define ZERO_ACC                                                         \
  _Pragma("unroll") for (int of = 0; of < 2; ++of)                       \
  _Pragma("unroll") for (int mf = 0; mf < 2; ++mf)                       \
      acc[of][mf] = (f32x4){0.f, 0.f, 0.f, 0.f};

// MFMA pass over a staged [m][k] swizzled f16 LDS tile with reg-resident W.
#define GEMM_LAYER(SRC, WREG)                                                     \
  {                                                                               \
    _Pragma("unroll") for (int ks = 0; ks < 8; ++ks) {                            \
      _Pragma("unroll") for (int mf = 0; mf < 2; ++mf) {                          \
        f16x8 bf = *(const f16x8*)((const char*)(SRC) + rowoff[mf] +              \
                                   (((ks * 64) + kb) ^ swz));                     \
        acc[0][mf] = __builtin_amdgcn_mfma_f32_16x16x32_f16(WREG[0][ks], bf,      \
                                                            acc[0][mf], 0, 0, 0); \
        acc[1][mf] = __builtin_amdgcn_mfma_f32_16x16x32_f16(WREG[1][ks], bf,      \
                                                            acc[1][mf], 0, 0, 0); \
      }                                                                           \
    }                                                                             \
  }

// bias + relu + cvt f16 + swizzled LDS store ([m][k] layout, k = this layer's o)
#define STORE_ACT(DST, BIAS)                                                      \
  _Pragma("unroll") for (int of = 0; of < 2; ++of)                                \
  _Pragma("unroll") for (int mf = 0; mf < 2; ++mf) {                              \
    f16x4 hh;                                                                     \
    _Pragma("unroll") for (int j = 0; j < 4; ++j)                                 \
        hh[j] = (f16)fmaxf(acc[of][mf][j] + BIAS[of][j], 0.f);                    \
    *(f16x4*)((char*)(DST) + (mf * 16 + r) * 512 + (obyte[of] ^ swz)) = hh;       \
  }

// Fused layers 1-3 + maxpool(n1) + layers 4-5.
// Grid (8 m-tiles of 32, 32 batches), 512 threads = 8 waves.
// Wave w owns output channels [32w, 32w+32); W-fragments live in VGPRs.
__global__ __launch_bounds__(512, 2) void k_fused(
    const float* __restrict__ b2, const float* __restrict__ b3,
    const float* __restrict__ b4, const float* __restrict__ b5,
    const float* __restrict__ sim, const float* __restrict__ c1,
    const f16* __restrict__ w2h, const f16* __restrict__ w3h,
    const f16* __restrict__ w4h, const f16* __restrict__ w5h,
    const float* __restrict__ w1t, float* __restrict__ out) {
  const int mt = blockIdx.x, b = blockIdx.y;
  const int mb = mt * 32;
  const int tid = threadIdx.x;
  const int w = tid >> 6, lane = tid & 63;
  const int g = lane >> 4, r = lane & 15;
  const int o0w = w * 32;

  __shared__ __align__(16) char y1l[32 * 512];  // [m][k] f16, XOR-swizzled
  __shared__ __align__(16) char y2l[32 * 512];
  __shared__ __align__(16) float w1c0s[256];

  if (tid < 256) w1c0s[tid] = w1t[tid];  // W1 column 0 (sim weight)

  // W2/W3 fragments -> registers (reused across all 64 n iterations)
  f16x8 wA[2][8], wB[2][8];
#pragma unroll
  for (int of = 0; of < 2; ++of)
#pragma unroll
    for (int ks = 0; ks < 8; ++ks) {
      int row = o0w + of * 16 + r;
      int col = ks * 32 + g * 8;
      wA[of][ks] = *(const f16x8*)(w2h + row * 256 + col);
      wB[of][ks] = *(const f16x8*)(w3h + row * 256 + col);
    }

  f32x4 bias2[2], bias3[2];
#pragma unroll
  for (int of = 0; of < 2; ++of) {
    bias2[of] = *(const f32x4*)(b2 + o0w + of * 16 + g * 4);
    bias3[of] = *(const f32x4*)(b3 + o0w + of * 16 + g * 4);
  }

  const int swz = (r & 7) << 4;
  const int rowoff[2] = {r * 512, (16 + r) * 512};
  const int kb = g * 16;
  const int obyte[2] = {(o0w + 0 + g * 4) * 2, (o0w + 16 + g * 4) * 2};

  // layer-1 producer mapping: thread -> (m row, 16-wide k chunk)
  const int m1 = tid >> 4;
  const int kc = (tid & 15) << 4;
  const int kc2 = kc * 2;
  char* y1wbase = y1l + m1 * 512;
  const int swz1 = (m1 & 7) << 4;
  const float* simP = sim + (b * N1) * N2 + mb;
  const float* c1P = c1 + (b * N1) * 256;

  f32x4 pool[2][2];
#pragma unroll
  for (int of = 0; of < 2; ++of)
#pragma unroll
    for (int mf = 0; mf < 2; ++mf) pool[of][mf] = (f32x4){0.f, 0.f, 0.f, 0.f};

  f32x4 acc[2][2];

  for (int n = 0; n < N1; ++n) {
    __syncthreads();  // y1l/y2l overwrite guard vs previous iteration readers
    // ---- layer 1: y1[k][m] = relu(w1c0[k]*sim[n][m] + c1[n][k]) -> f16 LDS
    {
      float simv = simP[n * N2 + m1];
      const float* c1p = c1P + n * 256 + kc;
      float v[16];
#pragma unroll
      for (int i = 0; i < 16; i += 4) {
        f32x4 c4 = *(const f32x4*)(c1p + i);
        f32x4 w4 = *(const f32x4*)(w1c0s + kc + i);
#pragma unroll
        for (int j = 0; j < 4; ++j) v[i + j] = fmaxf(fmaf(w4[j], simv, c4[j]), 0.f);
      }
      f16x8 h0, h1;
#pragma unroll
      for (int i = 0; i < 8; ++i) { h0[i] = (f16)v[i]; h1[i] = (f16)v[8 + i]; }
      *(f16x8*)(y1wbase + (kc2 ^ swz1)) = h0;
      *(f16x8*)(y1wbase + ((kc2 + 16) ^ swz1)) = h1;
    }
    __syncthreads();
    // ---- layer 2 (MFMA) + relu -> y2l
    ZERO_ACC;
    GEMM_LAYER(y1l, wA);
    STORE_ACT(y2l, bias2);
    __syncthreads();
    // ---- layer 3 (MFMA) + relu + pool
    ZERO_ACC;
    GEMM_LAYER(y2l, wB);
#pragma unroll
    for (int of = 0; of < 2; ++of)
#pragma unroll
      for (int mf = 0; mf < 2; ++mf)
#pragma unroll
        for (int j = 0; j < 4; ++j)
          pool[of][mf][j] =
              fmaxf(pool[of][mf][j], fmaxf(acc[of][mf][j] + bias3[of][j], 0.f));
  }

  // ---- tail: pooled tile -> y1l (f16), swap W4/W5 into the same registers
#pragma unroll
  for (int of = 0; of < 2; ++of)
#pragma unroll
    for (int mf = 0; mf < 2; ++mf) {
      f16x4 hh;
#pragma unroll
      for (int j = 0; j < 4; ++j) hh[j] = (f16)pool[of][mf][j];
      *(f16x4*)(y1l + (mf * 16 + r) * 512 + (obyte[of] ^ swz)) = hh;
    }
#pragma unroll
  for (int of = 0; of < 2; ++of) {
#pragma unroll
    for (int ks = 0; ks < 8; ++ks) {
      int row = o0w + of * 16 + r;
      int col = ks * 32 + g * 8;
      wA[of][ks] = *(const f16x8*)(w4h + row * 256 + col);
      wB[of][ks] = *(const f16x8*)(w5h + row * 256 + col);
    }
    bias2[of] = *(const f32x4*)(b4 + o0w + of * 16 + g * 4);
    bias3[of] = *(const f32x4*)(b5 + o0w + of * 16 + g * 4);
  }
  __syncthreads();
  // ---- layer 4 (MFMA) + relu -> y2l
  ZERO_ACC;
  GEMM_LAYER(y1l, wA);
  STORE_ACT(y2l, bias2);
  __syncthreads();
  // ---- layer 5 (MFMA, no relu) -> out f32 [b][o][m]
  ZERO_ACC;
  GEMM_LAYER(y2l, wB);
#pragma unroll
  for (int of = 0; of < 2; ++of)
#pragma unroll
    for (int mf = 0; mf < 2; ++mf) {
      int m = mb + mf * 16 + r;
      int ob = o0w + of * 16 + g * 4;
      float* op = out + ((size_t)b * 256 + ob) * 256 + m;
#pragma unroll
      for (int j = 0; j < 4; ++j) op[j * 256] = acc[of][mf][j] + bias3[of][j];
    }
}

extern "C" void kernel_launch(void* const* d_in, const int* in_sizes, int n_in,
                              void* d_out, int out_size, void* d_ws, size_t ws_size,
                              hipStream_t stream) {
  const float* sf = (const float*)d_in[0];
  const float* tf = (const float*)d_in[1];
  const float* seeds = (const float*)d_in[2];
  const float* W1 = (const float*)d_in[3];
  const float* b1 = (const float*)d_in[4];
  const float* W2 = (const float*)d_in[5];
  const float* b2 = (const float*)d_in[6];
  const float* W3 = (const float*)d_in[7];
  const float* b3 = (const float*)d_in[8];
  const float* W4 = (const float*)d_in[9];
  const float* b4 = (const float*)d_in[10];
  const float* W5 = (const float*)d_in[11];
  const float* b5 = (const float*)d_in[12];
  char* wsb = (char*)d_ws;
  float* w1t = (float*)(wsb + OFFB_W1T);
  float* invt = (float*)(wsb + OFFB_INVT);
  float* invs = (float*)(wsb + OFFB_INVS);
  float* sim = (float*)(wsb + OFFB_SIM);
  float* c1 = (float*)(wsb + OFFB_C1);
  f16* w2h = (f16*)(wsb + OFFB_W2H);
  f16* w3h = (f16*)(wsb + OFFB_W3H);
  f16* w4h = (f16*)(wsb + OFFB_W4H);
  f16* w5h = (f16*)(wsb + OFFB_W5H);
  float* out = (float*)d_out;

  k_prep_w1t<<<dim3(260), 256, 0, stream>>>(W1, w1t);
  k_half<<<dim3(256, 4), 256, 0, stream>>>(W2, W3, W4, W5, w2h, w3h, w4h, w5h);
  k_norms<<<dim3(BB), 256, 0, stream>>>(sf, tf, invt, invs);
  k_sim<<<dim3(N1, BB), 256, 0, stream>>>(tf, sf, invt, invs, sim);
  k_c1<<<dim3(N1, BB), 256, 0, stream>>>(tf, seeds, b1, w1t, c1);
  k_fused<<<dim3(8, BB), 512, 0, stream>>>(b2, b3, b4, b5, sim, c1,
                                           w2h, w3h, w4h, w5h, w1t, out);
}